// Round 2
// 351.460 us; speedup vs baseline: 1.0029x; 1.0029x over previous
//
#include <hip/hip_runtime.h>
#include <stdint.h>

// Problem constants: B=4, T=2048, C=1024, H=16, d=64, R=8. Inputs/outputs fp32.
#define T_LEN 2048
#define C_DIM 1024
#define NHEAD 16
#define DHEAD 64
#define QOFF  8388608L   // float-elem offset of q section in d_out
#define KOFF  16777216L  // float-elem offset of k section in d_out
#define SCALE_LOG2 0.18033688011112042f  // 0.125 * log2(e)

typedef float f32x4 __attribute__((ext_vector_type(4)));
typedef short bf16x8 __attribute__((ext_vector_type(8)));
typedef short s16x4 __attribute__((ext_vector_type(4)));
typedef unsigned short u16;

__device__ __forceinline__ float b2f(u16 h) {
  union { uint32_t u; float f; } v; v.u = ((uint32_t)h) << 16; return v.f;
}
__device__ __forceinline__ u16 f2b(float f) {
  union { float f; uint32_t u; } v; v.f = f;
  uint32_t r = v.u + 0x7fffu + ((v.u >> 16) & 1u);  // RNE
  return (u16)(r >> 16);
}
__device__ __forceinline__ u16 f2b_tr(float f) {  // truncation: 1 VALU op
  union { float f; uint32_t u; } v; v.f = f;
  return (u16)(v.u >> 16);
}
__device__ __forceinline__ void async16(const u16* g, u16* l) {
  __builtin_amdgcn_global_load_lds((const __attribute__((address_space(1))) void*)g,
                                   (__attribute__((address_space(3))) void*)l, 16, 0, 0);
}

#define MFMA16 __builtin_amdgcn_mfma_f32_16x16x32_bf16

// fp32 x -> bf16 canonical, 4 elems/thread.
__global__ __launch_bounds__(256) void convert_x(const float* __restrict__ xin,
                                                 u16* __restrict__ xc) {
  long i = ((long)blockIdx.x * 256 + threadIdx.x) * 4;
  f32x4 v = *(const f32x4*)(xin + i);
  s16x4 r;
  r[0] = (short)f2b(v[0]); r[1] = (short)f2b(v[1]);
  r[2] = (short)f2b(v[2]); r[3] = (short)f2b(v[3]);
  *(s16x4*)(xc + i) = r;
}

// W_eff = W + B*A (LoRA fold), fp32 in, bf16 out. K=1024, R=8.
__global__ __launch_bounds__(256) void prep_weff(const float* __restrict__ W,
                                                 const float* __restrict__ Bm,
                                                 const float* __restrict__ Aw,
                                                 u16* __restrict__ out, int total) {
  int i = blockIdx.x * 256 + threadIdx.x;
  if (i >= total) return;
  int n = i >> 10, k = i & 1023;
  float acc = W[i];
#pragma unroll
  for (int r = 0; r < 8; r++) acc += Bm[n * 8 + r] * Aw[r * 1024 + k];
  out[i] = f2b(acc);
}

// ---------------------------------------------------------------------------
// QKV GEMM: 256x256 tile, BK=64, 8 waves (2M x 4N), 4-phase counted-vmcnt
// schedule (T2 swizzle + T3/T4 pipeline + T5 setprio). C = A[8192,1024] x
// Bt[3072,1024]^T + bias; q/k -> fp32 d_out sections, k -> kc bf16, v -> vblk.
//
// LDS: [2 bufs][256 rows][64 cols] bf16 for A and B = 128 KiB. Chunk swizzle
// (16B chunks): LDS[row][c] = global[row][c ^ (row&7)] -- applied at the
// pre-swizzled global source of global_load_lds (dest stays linear, rule 21)
// and inverted on ds_read. Fragment reads are then bank-conflict-free.
//
// RACE-FREE staging invariant (R1 post-mortem: same-phase stage+read of one
// region raced via LDS-queue bypass, corrupting ~1 in 10^3 fragments):
//   stage region X only in a phase strictly AFTER the barrier that closes
//   X's last-reading phase. That barrier is crossed only after every wave's
//   MFMAs consumed its ds_reads (lgkmcnt), so no read of X can be pending.
// Read schedule:  A granules {0,2} read at P0, {1,3} at P2; B read P0+P1.
// Stage schedule (tile t+2 into the buffer being read -- distance 2, same
// parity): P1: A0,A2   P2: B0..B3   P3: A1,A3.
// One s_waitcnt vmcnt(8) per K-tile at P3 (8 newest = tile t+2 stay in
// flight; forces tile t+1 landed), made collective by the barrier after it.
// Every load gets 4-7 phases (~1000+ cyc) of latency tolerance.
// ---------------------------------------------------------------------------
__global__ __launch_bounds__(512, 2) void gemm256_qkv(const u16* __restrict__ A,
                                                      const u16* __restrict__ Bt,
                                                      const float* __restrict__ bias,
                                                      float* __restrict__ outf,
                                                      u16* __restrict__ kc,
                                                      u16* __restrict__ vblk) {
  __shared__ __align__(16) u16 ldsA[2][256 * 64];
  __shared__ __align__(16) u16 ldsB[2][256 * 64];
  const int t = threadIdx.x;
  const int lane = t & 63, l15 = lane & 15, quad = lane >> 4;
  const int w = t >> 6, wm = w >> 2, wn = w & 3;
  // XCD-aware bijective swizzle (384 % 8 == 0): each XCD gets 4 contiguous
  // M-rows (A panels 2 MB, L2-resident) x all 12 N-tiles.
  const int flat = blockIdx.x;
  const int swz = (flat & 7) * 48 + (flat >> 3);
  const int bx = swz % 12, by = swz / 12;
  const long rowA = (long)by * 256, rowB = (long)bx * 256;
  const u16* Ab = A + rowA * C_DIM;
  const u16* Bb = Bt + rowB * C_DIM;

  // staging: thread t covers chunk t of a 64x64 granule (row=t>>3, kchunk=t&7)
  const int sr = t >> 3;
  const int sk = ((t & 7) ^ (sr & 7)) * 8;  // pre-swizzled source k-offset
  const int sdst = t * 8;                   // linear LDS dest (rule 21)

#define STAGE_A(tt, gi) async16(Ab + (long)((gi) * 64 + sr) * C_DIM + (tt) * 64 + sk, \
                                &ldsA[(tt) & 1][(gi) * 4096 + sdst])
#define STAGE_B(tt, gi) async16(Bb + (long)((gi) * 64 + sr) * C_DIM + (tt) * 64 + sk, \
                                &ldsB[(tt) & 1][(gi) * 4096 + sdst])

  f32x4 acc[8][4];
#pragma unroll
  for (int i = 0; i < 8; i++)
#pragma unroll
    for (int j = 0; j < 4; j++) { f32x4 z = {0.f, 0.f, 0.f, 0.f}; acc[i][j] = z; }

  // prologue: tiles 0 and 1 fully issued; force tile 0 landed, keep tile 1
  // (8 newest) in flight.
#pragma unroll
  for (int gi = 0; gi < 4; gi++) { STAGE_A(0, gi); STAGE_B(0, gi); }
#pragma unroll
  for (int gi = 0; gi < 4; gi++) { STAGE_A(1, gi); STAGE_B(1, gi); }
  asm volatile("s_waitcnt vmcnt(8)" ::: "memory");
  __builtin_amdgcn_s_barrier();

  const int arow = wm * 128 + l15;  // + rh*64 + rg*16
  const int brow = wn * 64 + l15;   // + cg*16
  const int xsw = l15 & 7;          // read-side swizzle (row&7 == l15&7)

  bf16x8 af[4][2], bf[4][2];

  for (int kt = 0; kt < 16; kt++) {
    const u16* lA = ldsA[kt & 1];
    const u16* lB = ldsB[kt & 1];
    const bool st = (kt < 14);  // stage tile kt+2 (block-uniform branch)

    // ---- P0: read A-rh0 (8) + B-cg01 (4); no staging; MFMA (rh0,ch0)
#pragma unroll
    for (int rg = 0; rg < 4; rg++)
#pragma unroll
      for (int k = 0; k < 2; k++)
        af[rg][k] = *(const bf16x8*)&lA[(arow + rg * 16) * 64 + (((k * 4 + quad) ^ xsw) * 8)];
#pragma unroll
    for (int cg = 0; cg < 2; cg++)
#pragma unroll
      for (int k = 0; k < 2; k++)
        bf[cg][k] = *(const bf16x8*)&lB[(brow + cg * 16) * 64 + (((k * 4 + quad) ^ xsw) * 8)];
    __builtin_amdgcn_s_barrier();
    __builtin_amdgcn_s_setprio(1);
#pragma unroll
    for (int rg = 0; rg < 4; rg++)
#pragma unroll
      for (int cg = 0; cg < 2; cg++) {
        acc[rg][cg] = MFMA16(af[rg][0], bf[cg][0], acc[rg][cg], 0, 0, 0);
        acc[rg][cg] = MFMA16(af[rg][1], bf[cg][1], acc[rg][cg], 0, 0, 0);
      }
    __builtin_amdgcn_s_setprio(0);
    __builtin_amdgcn_s_barrier();

    // ---- P1: read B-cg23 (4); stage A0,A2(t+2) [A-rh0 retired at P0]; MFMA (rh0,ch1)
#pragma unroll
    for (int cg = 2; cg < 4; cg++)
#pragma unroll
      for (int k = 0; k < 2; k++)
        bf[cg][k] = *(const bf16x8*)&lB[(brow + cg * 16) * 64 + (((k * 4 + quad) ^ xsw) * 8)];
    if (st) { STAGE_A(kt + 2, 0); STAGE_A(kt + 2, 2); }
    __builtin_amdgcn_s_barrier();
    __builtin_amdgcn_s_setprio(1);
#pragma unroll
    for (int rg = 0; rg < 4; rg++)
#pragma unroll
      for (int cg = 2; cg < 4; cg++) {
        acc[rg][cg] = MFMA16(af[rg][0], bf[cg][0], acc[rg][cg], 0, 0, 0);
        acc[rg][cg] = MFMA16(af[rg][1], bf[cg][1], acc[rg][cg], 0, 0, 0);
      }
    __builtin_amdgcn_s_setprio(0);
    __builtin_amdgcn_s_barrier();

    // ---- P2: read A-rh1 (8); stage B0..B3(t+2) [B retired at P1]; MFMA (rh1,ch0)
#pragma unroll
    for (int rg = 0; rg < 4; rg++)
#pragma unroll
      for (int k = 0; k < 2; k++)
        af[rg][k] = *(const bf16x8*)&lA[(arow + 64 + rg * 16) * 64 + (((k * 4 + quad) ^ xsw) * 8)];
    if (st) { STAGE_B(kt + 2, 0); STAGE_B(kt + 2, 1); STAGE_B(kt + 2, 2); STAGE_B(kt + 2, 3); }
    __builtin_amdgcn_s_barrier();
    __builtin_amdgcn_s_setprio(1);
#pragma unroll
    for (int rg = 0; rg < 4; rg++)
#pragma unroll
      for (int cg = 0; cg < 2; cg++) {
        acc[4 + rg][cg] = MFMA16(af[rg][0], bf[cg][0], acc[4 + rg][cg], 0, 0, 0);
        acc[4 + rg][cg] = MFMA16(af[rg][1], bf[cg][1], acc[4 + rg][cg], 0, 0, 0);
      }
    __builtin_amdgcn_s_setprio(0);
    __builtin_amdgcn_s_barrier();

    // ---- P3: stage A1,A3(t+2) [A-rh1 retired at P2]; counted vmcnt; MFMA (rh1,ch1)
    if (st) {
      STAGE_A(kt + 2, 1); STAGE_A(kt + 2, 3);
      asm volatile("s_waitcnt vmcnt(8)" ::: "memory");  // tile t+1 landed
    } else {
      asm volatile("s_waitcnt vmcnt(0)" ::: "memory");  // drain for last tiles
    }
    __builtin_amdgcn_s_barrier();  // makes the per-wave vmcnt collective
    __builtin_amdgcn_s_setprio(1);
#pragma unroll
    for (int rg = 0; rg < 4; rg++)
#pragma unroll
      for (int cg = 2; cg < 4; cg++) {
        acc[4 + rg][cg] = MFMA16(af[rg][0], bf[cg][0], acc[4 + rg][cg], 0, 0, 0);
        acc[4 + rg][cg] = MFMA16(af[rg][1], bf[cg][1], acc[4 + rg][cg], 0, 0, 0);
      }
    __builtin_amdgcn_s_setprio(0);
    __builtin_amdgcn_s_barrier();
  }

  // epilogue (same semantics as the old MODE-0 path, 256x256 footprint)
  const int sec = bx >> 2;  // 0=q, 1=k, 2=v (block-uniform: 256-col tile in one 1024 section)
#pragma unroll
  for (int rg = 0; rg < 8; rg++) {
#pragma unroll
    for (int cg = 0; cg < 4; cg++) {
      int n = (int)rowB + wn * 64 + cg * 16 + l15;
      float bv = bias[n];
      int nc = n & 1023, h = nc >> 6, dd = nc & 63;
#pragma unroll
      for (int r = 0; r < 4; r++) {
        int m = (int)rowA + wm * 128 + rg * 16 + quad * 4 + r;  // C/D: row=quad*4+reg, col=l15
        float val = acc[rg][cg][r] + bv;
        int bb = m >> 11, tt2 = m & 2047, bh = bb * NHEAD + h;
        if (sec == 0) {
          outf[QOFF + (long)m * C_DIM + nc] = val;
        } else if (sec == 1) {
          outf[KOFF + (long)m * C_DIM + nc] = val;
          kc[(long)bh * (T_LEN * 64) + (long)tt2 * 64 + dd] = f2b(val);
        } else {
          vblk[(long)bh * (T_LEN * 64) + (long)(tt2 >> 6) * 4096 + dd * 64 + (tt2 & 63)] = f2b(val);
        }
      }
    }
  }
}

// C[M,N] = A[M,K]*Bt[N,K]^T + bias. A bf16, bias fp32, out fp32. 128x128 tile, BK=32.
// Kept (proven) for the projection GEMM, where a 256^2 grid would be 128 blocks
// = half the GPU idle at 1 block/CU. MODE 1: -> d_out[0,M*C) fp32.
template <int MODE>
__global__ __launch_bounds__(256) void gemm_bt(const u16* __restrict__ A,
                                               const u16* __restrict__ Bt,
                                               const float* __restrict__ bias,
                                               float* __restrict__ outf,
                                               u16* __restrict__ kc,
                                               u16* __restrict__ vblk, int K) {
  __shared__ __align__(16) u16 ldsA[128 * 32];
  __shared__ __align__(16) u16 ldsB[128 * 32];
  const int t = threadIdx.x;
  const int lane = t & 63, l15 = lane & 15, quad = lane >> 4, w = t >> 6;
  const int wr = (w >> 1) * 64, wc = (w & 1) * 64;
  const long rowA = (long)blockIdx.y * 128;
  const long rowB = (long)blockIdx.x * 128;
  const int srow = t >> 2, scol = (t & 3) * 8;

  f32x4 acc[4][4];
#pragma unroll
  for (int i = 0; i < 4; i++)
#pragma unroll
    for (int j = 0; j < 4; j++) { f32x4 z = {0.f, 0.f, 0.f, 0.f}; acc[i][j] = z; }

  const u16* Ab = A + rowA * K;
  const u16* Bb = Bt + rowB * K;
  for (int k0 = 0; k0 < K; k0 += 32) {
    __syncthreads();
    async16(Ab + (long)srow * K + k0 + scol, &ldsA[t * 8]);
    async16(Ab + (long)(srow + 64) * K + k0 + scol, &ldsA[2048 + t * 8]);
    async16(Bb + (long)srow * K + k0 + scol, &ldsB[t * 8]);
    async16(Bb + (long)(srow + 64) * K + k0 + scol, &ldsB[2048 + t * 8]);
    __syncthreads();
    bf16x8 af[4], bfr[4];
#pragma unroll
    for (int g = 0; g < 4; g++) {
      af[g]  = *(const bf16x8*)&ldsA[(wr + g * 16 + l15) * 32 + quad * 8];
      bfr[g] = *(const bf16x8*)&ldsB[(wc + g * 16 + l15) * 32 + quad * 8];
    }
#pragma unroll
    for (int i = 0; i < 4; i++)
#pragma unroll
      for (int j = 0; j < 4; j++)
        acc[i][j] = MFMA16(af[i], bfr[j], acc[i][j], 0, 0, 0);
  }

#pragma unroll
  for (int i = 0; i < 4; i++) {
#pragma unroll
    for (int j = 0; j < 4; j++) {
      int n = (int)rowB + wc + j * 16 + l15;
      float bv = bias[n];
#pragma unroll
      for (int r = 0; r < 4; r++) {
        int m = (int)rowA + wr + i * 16 + quad * 4 + r;  // C/D: row=quad*4+reg, col=l15
        float val = acc[i][j][r] + bv;
        if constexpr (MODE == 1) {
          outf[(long)m * C_DIM + n] = val;
        } else {
          int sec = n >> 10;
          int nc = n & 1023;
          int h = nc >> 6, dd = nc & 63;
          int bb = m >> 11, tt = m & 2047;
          int bh = bb * NHEAD + h;
          if (sec == 0) {
            outf[QOFF + (long)m * C_DIM + nc] = val;
          } else if (sec == 1) {
            outf[KOFF + (long)m * C_DIM + nc] = val;
            kc[(long)bh * (T_LEN * 64) + (long)tt * 64 + dd] = f2b(val);
          } else {
            vblk[(long)bh * (T_LEN * 64) + (long)(tt >> 6) * 4096 + dd * 64 + (tt & 63)] = f2b(val);
          }
        }
      }
    }
  }
}

// Flash attention v3: fixed-base softmax (m=0; scores bounded ~|15| so exp2 is
// overflow-safe) -> no running max, no shuffle reductions, no alpha rescale.
// Row-sum l via ones-column MFMA (same bf16 P as numerator -> truncation-pack
// bias cancels in o/l). BK=64, K/V staged via async16 with XOR chunk swizzle.
__global__ __launch_bounds__(256) void flash_attn(const float* __restrict__ qsec,
                                                  const u16* __restrict__ kc,
                                                  const u16* __restrict__ vblk,
                                                  u16* __restrict__ yb) {
  __shared__ __align__(16) u16 ldsK[64 * 64];
  __shared__ __align__(16) u16 ldsV[64 * 64];
  __shared__ __align__(16) u16 plds[4][32 * 72];  // per-wave P, stride 72 (16B-aligned)
  const int t = threadIdx.x;
  const int lane = t & 63, l15 = lane & 15, quad = lane >> 4, w = t >> 6;
  const int qt = 15 - (blockIdx.x >> 6);   // heavy q-tiles dispatch first (LPT)
  const int bh = blockIdx.x & 63;
  const int q0 = qt * 128;
  const int bb = bh >> 4, h = bh & 15;

  // Q A-frags, pre-scaled by 0.125*log2e (softmax uses exp2)
  const float* Qb = qsec + ((long)bb * T_LEN + q0 + w * 32) * C_DIM + h * DHEAD;
  bf16x8 qf[2][2];
#pragma unroll
  for (int rg = 0; rg < 2; rg++)
#pragma unroll
    for (int kk = 0; kk < 2; kk++) {
      const float* p = Qb + (long)(rg * 16 + l15) * C_DIM + kk * 32 + quad * 8;
      f32x4 a = *(const f32x4*)p, b = *(const f32x4*)(p + 4);
      bf16x8 r;
      r[0] = (short)f2b(a[0] * SCALE_LOG2); r[1] = (short)f2b(a[1] * SCALE_LOG2);
      r[2] = (short)f2b(a[2] * SCALE_LOG2); r[3] = (short)f2b(a[3] * SCALE_LOG2);
      r[4] = (short)f2b(b[0] * SCALE_LOG2); r[5] = (short)f2b(b[1] * SCALE_LOG2);
      r[6] = (short)f2b(b[2] * SCALE_LOG2); r[7] = (short)f2b(b[3] * SCALE_LOG2);
      qf[rg][kk] = r;
    }

  bf16x8 ones;
#pragma unroll
  for (int j = 0; j < 8; j++) ones[j] = (short)0x3F80;  // bf16 1.0

  f32x4 o[2][4];
  f32x4 ls[2];  // row-sum accumulator (all cols identical)
#pragma unroll
  for (int rg = 0; rg < 2; rg++) {
#pragma unroll
    for (int cg = 0; cg < 4; cg++) { f32x4 z = {0.f, 0.f, 0.f, 0.f}; o[rg][cg] = z; }
    f32x4 z = {0.f, 0.f, 0.f, 0.f}; ls[rg] = z;
  }

  const u16* kcb = kc + (long)bh * (T_LEN * 64);
  const u16* vbb = vblk + (long)bh * (T_LEN * 64);
  // staging source chunk offsets (swizzle: LDS[row][ch] = src[row][ch^(row&7)])
  const int l0 = t, l1 = 256 + t;
  const int s0c = ((l0 >> 3) * 8 + ((l0 & 7) ^ ((l0 >> 3) & 7))) * 8;
  const int s1c = ((l1 >> 3) * 8 + ((l1 & 7) ^ ((l1 >> 3) & 7))) * 8;

  const int qminw = q0 + w * 32;
  const int nkt = (q0 + 128) >> 6;
  for (int kt = 0; kt < nkt; kt++) {
    const int kb0 = kt * 64;
    __syncthreads();  // all reads of previous tile done
    {
      const u16* ks = kcb + (long)kb0 * 64;
      const u16* vs = vbb + (long)kt * 4096;
      async16(ks + s0c, &ldsK[l0 * 8]);
      async16(ks + s1c, &ldsK[l1 * 8]);
      async16(vs + s0c, &ldsV[l0 * 8]);
      async16(vs + s1c, &ldsV[l1 * 8]);
    }
    __syncthreads();  // staging drained (compiler emits vmcnt(0) before barrier)
    if (kb0 > qminw + 31) continue;  // tile fully above diagonal for this wave

    // S = Q K^T (scaled): s[rg][kg], cols kg*16+l15, rows qminw+rg*16+quad*4+r
    f32x4 s[2][4];
#pragma unroll
    for (int rg = 0; rg < 2; rg++)
#pragma unroll
      for (int kg = 0; kg < 4; kg++) { f32x4 z = {0.f, 0.f, 0.f, 0.f}; s[rg][kg] = z; }
#pragma unroll
    for (int kg = 0; kg < 4; kg++) {
      int row = kg * 16 + l15, sw = row & 7;
      bf16x8 kf0 = *(const bf16x8*)&ldsK[row * 64 + ((quad ^ sw) * 8)];
      bf16x8 kf1 = *(const bf16x8*)&ldsK[row * 64 + (((4 + quad) ^ sw) * 8)];
#pragma unroll
      for (int rg = 0; rg < 2; rg++) {
        s[rg][kg] = MFMA16(qf[rg][0], kf0, s[rg][kg], 0, 0, 0);
        s[rg][kg] = MFMA16(qf[rg][1], kf1, s[rg][kg], 0, 0, 0);
      }
    }
    const bool needMask = (kb0 + 63) > qminw;  // wave-uniform
#pragma unroll
    for (int rg = 0; rg < 2; rg++) {
#pragma unroll
      for (int r = 0; r < 4; r++) {
        float v0 = s[rg][0][r], v1 = s[rg][1][r], v2 = s[rg][2][r], v3 = s[rg][3][r];
        if (needMask) {
          int qrow = qminw + rg * 16 + quad * 4 + r;
          if (kb0 + l15 > qrow)      v0 = -3.0e38f;
          if (kb0 + 16 + l15 > qrow) v1 = -3.0e38f;
          if (kb0 + 32 + l15 > qrow) v2 = -3.0e38f;
          if (kb0 + 48 + l15 > qrow) v3 = -3.0e38f;
        }
        // fixed-base: p = exp2(s), no max/alpha; exp2(-3e38)=0 handles the mask
        int prow = rg * 16 + quad * 4 + r;
        plds[w][prow * 72 + l15]      = f2b_tr(exp2f(v0));
        plds[w][prow * 72 + 16 + l15] = f2b_tr(exp2f(v1));
        plds[w][prow * 72 + 32 + l15] = f2b_tr(exp2f(v2));
        plds[w][prow * 72 + 48 + l15] = f2b_tr(exp2f(v3));
      }
    }
    asm volatile("s_waitcnt lgkmcnt(0)" ::: "memory");  // wave-local P visible
    bf16x8 pf[2][2];
#pragma unroll
    for (int rg = 0; rg < 2; rg++)
#pragma unroll
      for (int kk = 0; kk < 2; kk++)
        pf[rg][kk] = *(const bf16x8*)&plds[w][(rg * 16 + l15) * 72 + kk * 32 + quad * 8];
    // l-accumulate via ones-column MFMA (rows match o's C-layout rows)
#pragma unroll
    for (int rg = 0; rg < 2; rg++) {
      ls[rg] = MFMA16(pf[rg][0], ones, ls[rg], 0, 0, 0);
      ls[rg] = MFMA16(pf[rg][1], ones, ls[rg], 0, 0, 0);
    }
#pragma unroll
    for (int cg = 0; cg < 4; cg++) {
      int row = cg * 16 + l15, sw = row & 7;
      bf16x8 vf0 = *(const bf16x8*)&ldsV[row * 64 + ((quad ^ sw) * 8)];
      bf16x8 vf1 = *(const bf16x8*)&ldsV[row * 64 + (((4 + quad) ^ sw) * 8)];
#pragma unroll
      for (int rg = 0; rg < 2; rg++) {
        o[rg][cg] = MFMA16(pf[rg][0], vf0, o[rg][cg], 0, 0, 0);
        o[rg][cg] = MFMA16(pf[rg][1], vf1, o[rg][cg], 0, 0, 0);
      }
    }
  }
  // epilogue -> yb bf16 [b*T + t][C]
#pragma unroll
  for (int rg = 0; rg < 2; rg++) {
#pragma unroll
    for (int r = 0; r < 4; r++) {
      float inv = 1.0f / ls[rg][r];
      int tt = q0 + w * 32 + rg * 16 + quad * 4 + r;
      long base = ((long)bb * T_LEN + tt) * C_DIM + h * DHEAD;
#pragma unroll
      for (int cg = 0; cg < 4; cg++)
        yb[base + cg * 16 + l15] = f2b(o[rg][cg][r] * inv);
    }
  }
}

extern "C" void kernel_launch(void* const* d_in, const int* in_sizes, int n_in,
                              void* d_out, int out_size, void* d_ws, size_t ws_size,
                              hipStream_t stream) {
  const float* x  = (const float*)d_in[0];
  const float* w1 = (const float*)d_in[1];
  const float* b1 = (const float*)d_in[2];
  const float* A1 = (const float*)d_in[3];
  const float* B1 = (const float*)d_in[4];
  const float* w2 = (const float*)d_in[5];
  const float* b2 = (const float*)d_in[6];
  const float* A2 = (const float*)d_in[7];
  const float* B2 = (const float*)d_in[8];
  float* outf = (float*)d_out;
  u16* outb16 = (u16*)d_out;

  // ws (u16 elems), max footprint 25.2 MB (proven in R3/R4):
  u16* ws  = (u16*)d_ws;
  u16* w2e = ws;                  // [0, 1M)      bf16 W2_eff
  u16* w1e = ws + 1048576;        // [1M, 4M)     bf16 W1_eff (dead after gemm1)
  u16* xc  = ws + 4194304;        // [4M, 12.5M)  bf16 x (dead after gemm1)
  u16* yb  = ws + 1048576;        // aliases w1e/xc head; written post-gemm1
  // d_out out-section (fp32 bytes [0,32M)) used as bf16 scratch until gemm2:
  u16* vblk = outb16;             // bytes [0,16M): V tile-blocked [bh][kt][dd][tk]
  u16* kcp  = outb16 + 8388608;   // bytes [16M,32M): K packed [bh][t][64]

  convert_x<<<8192, 256, 0, stream>>>(x, xc);
  prep_weff<<<12288, 256, 0, stream>>>(w1, B1, A1, w1e, 3072 * 1024);
  prep_weff<<<4096, 256, 0, stream>>>(w2, B2, A2, w2e, 1024 * 1024);
  gemm256_qkv<<<384, 512, 0, stream>>>(xc, w1e, b1, outf, kcp, vblk);
  flash_attn<<<1024, 256, 0, stream>>>(outf + QOFF, kcp, vblk, yb);
  gemm_bt<1><<<dim3(8, 64), 256, 0, stream>>>(yb, w2e, b2, outf, nullptr, nullptr, 1024);
}

// Round 3
// 350.587 us; speedup vs baseline: 1.0054x; 1.0025x over previous
//
#include <hip/hip_runtime.h>
#include <stdint.h>

// Problem constants: B=4, T=2048, C=1024, H=16, d=64, R=8. Inputs/outputs fp32.
#define T_LEN 2048
#define C_DIM 1024
#define NHEAD 16
#define DHEAD 64
#define QOFF  8388608L   // float-elem offset of q section in d_out
#define KOFF  16777216L  // float-elem offset of k section in d_out
#define SCALE_LOG2 0.18033688011112042f  // 0.125 * log2(e)

typedef float f32x4 __attribute__((ext_vector_type(4)));
typedef short bf16x8 __attribute__((ext_vector_type(8)));
typedef short s16x4 __attribute__((ext_vector_type(4)));
typedef unsigned short u16;

__device__ __forceinline__ float b2f(u16 h) {
  union { uint32_t u; float f; } v; v.u = ((uint32_t)h) << 16; return v.f;
}
__device__ __forceinline__ u16 f2b(float f) {
  union { float f; uint32_t u; } v; v.f = f;
  uint32_t r = v.u + 0x7fffu + ((v.u >> 16) & 1u);  // RNE
  return (u16)(r >> 16);
}
__device__ __forceinline__ u16 f2b_tr(float f) {  // truncation: 1 VALU op
  union { float f; uint32_t u; } v; v.f = f;
  return (u16)(v.u >> 16);
}
__device__ __forceinline__ void async16(const u16* g, u16* l) {
  __builtin_amdgcn_global_load_lds((const __attribute__((address_space(1))) void*)g,
                                   (__attribute__((address_space(3))) void*)l, 16, 0, 0);
}

#define MFMA16 __builtin_amdgcn_mfma_f32_16x16x32_bf16

// fp32 x -> bf16 canonical, 4 elems/thread.
__global__ __launch_bounds__(256) void convert_x(const float* __restrict__ xin,
                                                 u16* __restrict__ xc) {
  long i = ((long)blockIdx.x * 256 + threadIdx.x) * 4;
  f32x4 v = *(const f32x4*)(xin + i);
  s16x4 r;
  r[0] = (short)f2b(v[0]); r[1] = (short)f2b(v[1]);
  r[2] = (short)f2b(v[2]); r[3] = (short)f2b(v[3]);
  *(s16x4*)(xc + i) = r;
}

// W_eff = W + B*A (LoRA fold), fp32 in, bf16 out. K=1024, R=8.
__global__ __launch_bounds__(256) void prep_weff(const float* __restrict__ W,
                                                 const float* __restrict__ Bm,
                                                 const float* __restrict__ Aw,
                                                 u16* __restrict__ out, int total) {
  int i = blockIdx.x * 256 + threadIdx.x;
  if (i >= total) return;
  int n = i >> 10, k = i & 1023;
  float acc = W[i];
#pragma unroll
  for (int r = 0; r < 8; r++) acc += Bm[n * 8 + r] * Aw[r * 1024 + k];
  out[i] = f2b(acc);
}

// C[M,N] = A[M,K]*Bt[N,K]^T + bias. A bf16, bias fp32, out fp32. 128x128 tile, BK=32.
// Proven R0 kernel (108 us for MODE 0), restored unchanged after the 256^2
// experiment regressed (R2: 121 us -- 1 block/CU, 1.5-round grid tail).
// MODE 0: q/k -> d_out fp32 sections; k also -> kc bf16 [bh][t][64];
//         v -> vblk bf16 [bh][t>>6][dd][t&63]. MODE 1: -> d_out[0,M*C) fp32.
template <int MODE>
__global__ __launch_bounds__(256) void gemm_bt(const u16* __restrict__ A,
                                               const u16* __restrict__ Bt,
                                               const float* __restrict__ bias,
                                               float* __restrict__ outf,
                                               u16* __restrict__ kc,
                                               u16* __restrict__ vblk, int K) {
  __shared__ __align__(16) u16 ldsA[128 * 32];
  __shared__ __align__(16) u16 ldsB[128 * 32];
  const int t = threadIdx.x;
  const int lane = t & 63, l15 = lane & 15, quad = lane >> 4, w = t >> 6;
  const int wr = (w >> 1) * 64, wc = (w & 1) * 64;
  const long rowA = (long)blockIdx.y * 128;
  const long rowB = (long)blockIdx.x * 128;
  const int srow = t >> 2, scol = (t & 3) * 8;

  f32x4 acc[4][4];
#pragma unroll
  for (int i = 0; i < 4; i++)
#pragma unroll
    for (int j = 0; j < 4; j++) { f32x4 z = {0.f, 0.f, 0.f, 0.f}; acc[i][j] = z; }

  const u16* Ab = A + rowA * K;
  const u16* Bb = Bt + rowB * K;
  for (int k0 = 0; k0 < K; k0 += 32) {
    __syncthreads();
    async16(Ab + (long)srow * K + k0 + scol, &ldsA[t * 8]);
    async16(Ab + (long)(srow + 64) * K + k0 + scol, &ldsA[2048 + t * 8]);
    async16(Bb + (long)srow * K + k0 + scol, &ldsB[t * 8]);
    async16(Bb + (long)(srow + 64) * K + k0 + scol, &ldsB[2048 + t * 8]);
    __syncthreads();
    bf16x8 af[4], bfr[4];
#pragma unroll
    for (int g = 0; g < 4; g++) {
      af[g]  = *(const bf16x8*)&ldsA[(wr + g * 16 + l15) * 32 + quad * 8];
      bfr[g] = *(const bf16x8*)&ldsB[(wc + g * 16 + l15) * 32 + quad * 8];
    }
#pragma unroll
    for (int i = 0; i < 4; i++)
#pragma unroll
      for (int j = 0; j < 4; j++)
        acc[i][j] = MFMA16(af[i], bfr[j], acc[i][j], 0, 0, 0);
  }

#pragma unroll
  for (int i = 0; i < 4; i++) {
#pragma unroll
    for (int j = 0; j < 4; j++) {
      int n = (int)rowB + wc + j * 16 + l15;
      float bv = bias[n];
#pragma unroll
      for (int r = 0; r < 4; r++) {
        int m = (int)rowA + wr + i * 16 + quad * 4 + r;  // C/D: row=quad*4+reg, col=l15
        float val = acc[i][j][r] + bv;
        if constexpr (MODE == 1) {
          outf[(long)m * C_DIM + n] = val;
        } else {
          int sec = n >> 10;  // 0=q,1=k,2=v (block-uniform)
          int nc = n & 1023;
          int h = nc >> 6, dd = nc & 63;
          int bb = m >> 11, tt = m & 2047;
          int bh = bb * NHEAD + h;
          if (sec == 0) {
            outf[QOFF + (long)m * C_DIM + nc] = val;
          } else if (sec == 1) {
            outf[KOFF + (long)m * C_DIM + nc] = val;
            kc[(long)bh * (T_LEN * 64) + (long)tt * 64 + dd] = f2b(val);
          } else {
            vblk[(long)bh * (T_LEN * 64) + (long)(tt >> 6) * 4096 + dd * 64 + (tt & 63)] = f2b(val);
          }
        }
      }
    }
  }
}

// Flash attention v3 + double-buffered K/V staging (this round's one change).
// Fixed-base softmax (m=0; scores bounded ~|15| so exp2 is overflow-safe) ->
// no running max, no shuffle reductions, no alpha rescale. Row-sum l via
// ones-column MFMA. BK=64, XOR chunk swizzle on K/V.
//
// Staging schedule (T14 issue-early / drain-late, catalog min-2-phase):
//   prologue: stage tile0 -> buf0; vmcnt(0); barrier
//   iter kt:  stage tile kt+1 -> buf^1   (issued BEFORE compute)
//             compute from buf[cur]
//             vmcnt(0); barrier          (tile kt+1 landed; collective)
// Race check (R1 invariant): the stage into buf^1 is issued only after the
// barrier that closed buf^1's last-reading iteration (kt-1) -- every wave's
// ds_reads of buf^1 were consumed by its MFMAs before that barrier, so no
// read can be pending when the DMA write lands. The per-tile HBM/L2 drain
// (~400-800 cy) now hides under the ~600-cy compute phase instead of being
// serially exposed between two barriers.
__global__ __launch_bounds__(256) void flash_attn(const float* __restrict__ qsec,
                                                  const u16* __restrict__ kc,
                                                  const u16* __restrict__ vblk,
                                                  u16* __restrict__ yb) {
  __shared__ __align__(16) u16 ldsK[2][64 * 64];
  __shared__ __align__(16) u16 ldsV[2][64 * 64];
  __shared__ __align__(16) u16 plds[4][32 * 72];  // per-wave P, stride 72 (16B-aligned)
  const int t = threadIdx.x;
  const int lane = t & 63, l15 = lane & 15, quad = lane >> 4, w = t >> 6;
  const int qt = 15 - (blockIdx.x >> 6);   // heavy q-tiles dispatch first (LPT)
  const int bh = blockIdx.x & 63;
  const int q0 = qt * 128;
  const int bb = bh >> 4, h = bh & 15;

  // Q A-frags, pre-scaled by 0.125*log2e (softmax uses exp2)
  const float* Qb = qsec + ((long)bb * T_LEN + q0 + w * 32) * C_DIM + h * DHEAD;
  bf16x8 qf[2][2];
#pragma unroll
  for (int rg = 0; rg < 2; rg++)
#pragma unroll
    for (int kk = 0; kk < 2; kk++) {
      const float* p = Qb + (long)(rg * 16 + l15) * C_DIM + kk * 32 + quad * 8;
      f32x4 a = *(const f32x4*)p, b = *(const f32x4*)(p + 4);
      bf16x8 r;
      r[0] = (short)f2b(a[0] * SCALE_LOG2); r[1] = (short)f2b(a[1] * SCALE_LOG2);
      r[2] = (short)f2b(a[2] * SCALE_LOG2); r[3] = (short)f2b(a[3] * SCALE_LOG2);
      r[4] = (short)f2b(b[0] * SCALE_LOG2); r[5] = (short)f2b(b[1] * SCALE_LOG2);
      r[6] = (short)f2b(b[2] * SCALE_LOG2); r[7] = (short)f2b(b[3] * SCALE_LOG2);
      qf[rg][kk] = r;
    }

  bf16x8 ones;
#pragma unroll
  for (int j = 0; j < 8; j++) ones[j] = (short)0x3F80;  // bf16 1.0

  f32x4 o[2][4];
  f32x4 ls[2];  // row-sum accumulator (all cols identical)
#pragma unroll
  for (int rg = 0; rg < 2; rg++) {
#pragma unroll
    for (int cg = 0; cg < 4; cg++) { f32x4 z = {0.f, 0.f, 0.f, 0.f}; o[rg][cg] = z; }
    f32x4 z = {0.f, 0.f, 0.f, 0.f}; ls[rg] = z;
  }

  const u16* kcb = kc + (long)bh * (T_LEN * 64);
  const u16* vbb = vblk + (long)bh * (T_LEN * 64);
  // staging source chunk offsets (swizzle: LDS[row][ch] = src[row][ch^(row&7)])
  const int l0 = t, l1 = 256 + t;
  const int s0c = ((l0 >> 3) * 8 + ((l0 & 7) ^ ((l0 >> 3) & 7))) * 8;
  const int s1c = ((l1 >> 3) * 8 + ((l1 & 7) ^ ((l1 >> 3) & 7))) * 8;

  const int qminw = q0 + w * 32;
  const int nkt = (q0 + 128) >> 6;

#define KV_STAGE(kt_, b_) do {                                        \
    const u16* ks_ = kcb + (long)(kt_) * 4096;                        \
    const u16* vs_ = vbb + (long)(kt_) * 4096;                        \
    async16(ks_ + s0c, &ldsK[b_][l0 * 8]);                            \
    async16(ks_ + s1c, &ldsK[b_][l1 * 8]);                            \
    async16(vs_ + s0c, &ldsV[b_][l0 * 8]);                            \
    async16(vs_ + s1c, &ldsV[b_][l1 * 8]);                            \
  } while (0)

  KV_STAGE(0, 0);
  asm volatile("s_waitcnt vmcnt(0)" ::: "memory");
  __builtin_amdgcn_s_barrier();

  for (int kt = 0; kt < nkt; kt++) {
    const int kb0 = kt * 64;
    const int cur = kt & 1;
    if (kt + 1 < nkt) KV_STAGE(kt + 1, cur ^ 1);  // issue-early: hides under compute

    if (kb0 <= qminw + 31) {  // tile not fully above diagonal for this wave
      // S = Q K^T (scaled): s[rg][kg], cols kg*16+l15, rows qminw+rg*16+quad*4+r
      f32x4 s[2][4];
#pragma unroll
      for (int rg = 0; rg < 2; rg++)
#pragma unroll
        for (int kg = 0; kg < 4; kg++) { f32x4 z = {0.f, 0.f, 0.f, 0.f}; s[rg][kg] = z; }
#pragma unroll
      for (int kg = 0; kg < 4; kg++) {
        int row = kg * 16 + l15, sw = row & 7;
        bf16x8 kf0 = *(const bf16x8*)&ldsK[cur][row * 64 + ((quad ^ sw) * 8)];
        bf16x8 kf1 = *(const bf16x8*)&ldsK[cur][row * 64 + (((4 + quad) ^ sw) * 8)];
#pragma unroll
        for (int rg = 0; rg < 2; rg++) {
          s[rg][kg] = MFMA16(qf[rg][0], kf0, s[rg][kg], 0, 0, 0);
          s[rg][kg] = MFMA16(qf[rg][1], kf1, s[rg][kg], 0, 0, 0);
        }
      }
      const bool needMask = (kb0 + 63) > qminw;  // wave-uniform
#pragma unroll
      for (int rg = 0; rg < 2; rg++) {
#pragma unroll
        for (int r = 0; r < 4; r++) {
          float v0 = s[rg][0][r], v1 = s[rg][1][r], v2 = s[rg][2][r], v3 = s[rg][3][r];
          if (needMask) {
            int qrow = qminw + rg * 16 + quad * 4 + r;
            if (kb0 + l15 > qrow)      v0 = -3.0e38f;
            if (kb0 + 16 + l15 > qrow) v1 = -3.0e38f;
            if (kb0 + 32 + l15 > qrow) v2 = -3.0e38f;
            if (kb0 + 48 + l15 > qrow) v3 = -3.0e38f;
          }
          // fixed-base: p = exp2(s), no max/alpha; exp2(-3e38)=0 handles the mask
          int prow = rg * 16 + quad * 4 + r;
          plds[w][prow * 72 + l15]      = f2b_tr(exp2f(v0));
          plds[w][prow * 72 + 16 + l15] = f2b_tr(exp2f(v1));
          plds[w][prow * 72 + 32 + l15] = f2b_tr(exp2f(v2));
          plds[w][prow * 72 + 48 + l15] = f2b_tr(exp2f(v3));
        }
      }
      asm volatile("s_waitcnt lgkmcnt(0)" ::: "memory");  // wave-local P visible
      bf16x8 pf[2][2];
#pragma unroll
      for (int rg = 0; rg < 2; rg++)
#pragma unroll
        for (int kk = 0; kk < 2; kk++)
          pf[rg][kk] = *(const bf16x8*)&plds[w][(rg * 16 + l15) * 72 + kk * 32 + quad * 8];
      // l-accumulate via ones-column MFMA (rows match o's C-layout rows)
#pragma unroll
      for (int rg = 0; rg < 2; rg++) {
        ls[rg] = MFMA16(pf[rg][0], ones, ls[rg], 0, 0, 0);
        ls[rg] = MFMA16(pf[rg][1], ones, ls[rg], 0, 0, 0);
      }
#pragma unroll
      for (int cg = 0; cg < 4; cg++) {
        int row = cg * 16 + l15, sw = row & 7;
        bf16x8 vf0 = *(const bf16x8*)&ldsV[cur][row * 64 + ((quad ^ sw) * 8)];
        bf16x8 vf1 = *(const bf16x8*)&ldsV[cur][row * 64 + (((4 + quad) ^ sw) * 8)];
#pragma unroll
        for (int rg = 0; rg < 2; rg++) {
          o[rg][cg] = MFMA16(pf[rg][0], vf0, o[rg][cg], 0, 0, 0);
          o[rg][cg] = MFMA16(pf[rg][1], vf1, o[rg][cg], 0, 0, 0);
        }
      }
    }

    asm volatile("s_waitcnt vmcnt(0)" ::: "memory");  // tile kt+1 landed
    __builtin_amdgcn_s_barrier();                     // collective; closes reads of buf[cur]
  }

  // epilogue -> yb bf16 [b*T + t][C]
#pragma unroll
  for (int rg = 0; rg < 2; rg++) {
#pragma unroll
    for (int r = 0; r < 4; r++) {
      float inv = 1.0f / ls[rg][r];
      int tt = q0 + w * 32 + rg * 16 + quad * 4 + r;
      long base = ((long)bb * T_LEN + tt) * C_DIM + h * DHEAD;
#pragma unroll
      for (int cg = 0; cg < 4; cg++)
        yb[base + cg * 16 + l15] = f2b(o[rg][cg][r] * inv);
    }
  }
}

extern "C" void kernel_launch(void* const* d_in, const int* in_sizes, int n_in,
                              void* d_out, int out_size, void* d_ws, size_t ws_size,
                              hipStream_t stream) {
  const float* x  = (const float*)d_in[0];
  const float* w1 = (const float*)d_in[1];
  const float* b1 = (const float*)d_in[2];
  const float* A1 = (const float*)d_in[3];
  const float* B1 = (const float*)d_in[4];
  const float* w2 = (const float*)d_in[5];
  const float* b2 = (const float*)d_in[6];
  const float* A2 = (const float*)d_in[7];
  const float* B2 = (const float*)d_in[8];
  float* outf = (float*)d_out;
  u16* outb16 = (u16*)d_out;

  // ws (u16 elems), max footprint 25.2 MB (proven in R3/R4):
  u16* ws  = (u16*)d_ws;
  u16* w2e = ws;                  // [0, 1M)      bf16 W2_eff
  u16* w1e = ws + 1048576;        // [1M, 4M)     bf16 W1_eff (dead after gemm1)
  u16* xc  = ws + 4194304;        // [4M, 12.5M)  bf16 x (dead after gemm1)
  u16* yb  = ws + 1048576;        // aliases w1e/xc head; written post-gemm1
  // d_out out-section (fp32 bytes [0,32M)) used as bf16 scratch until gemm2:
  u16* vblk = outb16;             // bytes [0,16M): V tile-blocked [bh][kt][dd][tk]
  u16* kcp  = outb16 + 8388608;   // bytes [16M,32M): K packed [bh][t][64]

  convert_x<<<8192, 256, 0, stream>>>(x, xc);
  prep_weff<<<12288, 256, 0, stream>>>(w1, B1, A1, w1e, 3072 * 1024);
  prep_weff<<<4096, 256, 0, stream>>>(w2, B2, A2, w2e, 1024 * 1024);
  gemm_bt<0><<<dim3(24, 64), 256, 0, stream>>>(xc, w1e, b1, outf, kcp, vblk, 1024);
  flash_attn<<<1024, 256, 0, stream>>>(outf + QOFF, kcp, vblk, yb);
  gemm_bt<1><<<dim3(8, 64), 256, 0, stream>>>(yb, w2e, b2, outf, nullptr, nullptr, 1024);
}